// Round 1
// baseline (573.364 us; speedup 1.0000x reference)
//
#include <hip/hip_runtime.h>
#include <hip/hip_bf16.h>

#define LQ     1024
#define BATCH  4
#define DMODEL 1024
#define NH     16
#define DH     64
#define MROWS  (LQ * BATCH)

using f32x4 = __attribute__((ext_vector_type(4))) float;
using s16x8 = __attribute__((ext_vector_type(8))) short;

static __device__ __forceinline__ unsigned short f2b(float f) {
    union { float f; unsigned u; } v; v.f = f;
    unsigned r = v.u + 0x7fffu + ((v.u >> 16) & 1u);   // RNE
    return (unsigned short)(r >> 16);
}
static __device__ __forceinline__ unsigned pack2(float lo, float hi) {
    return (unsigned)f2b(lo) | ((unsigned)f2b(hi) << 16);
}

// C[M=4096, N=1024] = A[M,K=1024] * W[N,K]^T  (optionally scaled), bf16 MFMA.
// A_F32: A is f32 (converted to bf16 during LDS staging) else bf16.
// OUT_F32: C written as f32 (to d_out) else bf16 (to workspace).
template<bool A_F32, bool OUT_F32>
__global__ __launch_bounds__(256) void gemm_bt(const void* __restrict__ Ap,
                                               const float* __restrict__ W,
                                               void* __restrict__ Cp,
                                               float scale) {
    __shared__ unsigned short a_lds[128][40];   // +8 pad -> 2-way banks (free)
    __shared__ unsigned short b_lds[128][40];
    const int tid  = threadIdx.x;
    const int lane = tid & 63;
    const int w    = tid >> 6;
    const int wr   = (w >> 1) * 64;
    const int wc   = (w & 1) * 64;
    const int lr   = lane & 15;
    const int ko   = (lane >> 4) * 8;
    const int bx   = blockIdx.x * 128;
    const int by   = blockIdx.y * 128;
    const int srow = tid >> 1;
    const int sch  = (tid & 1) * 16;

    f32x4 acc[4][4] = {};

    for (int k0 = 0; k0 < DMODEL; k0 += 32) {
        // ---- stage A tile (128x32) ----
        if (A_F32) {
            const float* src = (const float*)Ap + (size_t)(bx + srow) * DMODEL + k0 + sch;
            float4 f0 = ((const float4*)src)[0];
            float4 f1 = ((const float4*)src)[1];
            float4 f2 = ((const float4*)src)[2];
            float4 f3 = ((const float4*)src)[3];
            *(uint4*)&a_lds[srow][sch]     = make_uint4(pack2(f0.x,f0.y), pack2(f0.z,f0.w),
                                                        pack2(f1.x,f1.y), pack2(f1.z,f1.w));
            *(uint4*)&a_lds[srow][sch + 8] = make_uint4(pack2(f2.x,f2.y), pack2(f2.z,f2.w),
                                                        pack2(f3.x,f3.y), pack2(f3.z,f3.w));
        } else {
            const unsigned short* src = (const unsigned short*)Ap + (size_t)(bx + srow) * DMODEL + k0 + sch;
            *(uint4*)&a_lds[srow][sch]     = ((const uint4*)src)[0];
            *(uint4*)&a_lds[srow][sch + 8] = ((const uint4*)src)[1];
        }
        // ---- stage W tile (128x32) ----
        {
            const float* src = W + (size_t)(by + srow) * DMODEL + k0 + sch;
            float4 f0 = ((const float4*)src)[0];
            float4 f1 = ((const float4*)src)[1];
            float4 f2 = ((const float4*)src)[2];
            float4 f3 = ((const float4*)src)[3];
            *(uint4*)&b_lds[srow][sch]     = make_uint4(pack2(f0.x,f0.y), pack2(f0.z,f0.w),
                                                        pack2(f1.x,f1.y), pack2(f1.z,f1.w));
            *(uint4*)&b_lds[srow][sch + 8] = make_uint4(pack2(f2.x,f2.y), pack2(f2.z,f2.w),
                                                        pack2(f3.x,f3.y), pack2(f3.z,f3.w));
        }
        __syncthreads();

        s16x8 af[4], bfr[4];
#pragma unroll
        for (int m = 0; m < 4; ++m) af[m]  = *(const s16x8*)&a_lds[wr + m * 16 + lr][ko];
#pragma unroll
        for (int n = 0; n < 4; ++n) bfr[n] = *(const s16x8*)&b_lds[wc + n * 16 + lr][ko];
#pragma unroll
        for (int m = 0; m < 4; ++m)
#pragma unroll
            for (int n = 0; n < 4; ++n)
                acc[m][n] = __builtin_amdgcn_mfma_f32_16x16x32_bf16(af[m], bfr[n], acc[m][n], 0, 0, 0);
        __syncthreads();
    }

    // ---- epilogue ----
    const int orow0 = bx + wr + 4 * (lane >> 4);
#pragma unroll
    for (int m = 0; m < 4; ++m) {
#pragma unroll
        for (int n = 0; n < 4; ++n) {
            const int col = by + wc + n * 16 + lr;
#pragma unroll
            for (int j = 0; j < 4; ++j) {
                const int row = orow0 + m * 16 + j;
                const float v = acc[m][n][j] * scale;
                if (OUT_F32) ((float*)Cp)[(size_t)row * DMODEL + col] = v;
                else ((unsigned short*)Cp)[(size_t)row * DMODEL + col] = f2b(v);
            }
        }
    }
}

// Fused causal attention + coverage. Block = (qt, b): 16 q-rows of one batch,
// loops over all 16 heads. Exact softmax (full row in LDS), coverage in regs.
__global__ __launch_bounds__(256) void attn_cov(const unsigned short* __restrict__ qb,
                                                const unsigned short* __restrict__ kb,
                                                const unsigned short* __restrict__ vb,
                                                unsigned short* __restrict__ ao,
                                                float* __restrict__ cov) {
    __shared__ float          s_lds[16][1025];   // scores, f32
    __shared__ unsigned short p_lds[16][1032];   // probs, bf16
    __shared__ unsigned short vt_lds[64][136];   // V^T tile: [d][k_local]

    const int tid  = threadIdx.x;
    const int lane = tid & 63;
    const int w    = tid >> 6;
    const int qt   = blockIdx.x;   // 0..63
    const int b    = blockIdx.y;   // 0..3
    const int lr   = lane & 15;
    const int lk8  = (lane >> 4) * 8;
    const int qmax = qt * 16 + 15;

    float creg[4][16];
#pragma unroll
    for (int r = 0; r < 4; ++r)
#pragma unroll
        for (int i = 0; i < 16; ++i) creg[r][i] = 0.f;

    for (int h = 0; h < NH; ++h) {
        // ---- QK^T (causal: only k-tiles t <= qt) ----
        const size_t qbase = ((size_t)(qt * 16 + lr) * BATCH + b) * DMODEL + h * DH + lk8;
        const s16x8 aq0 = *(const s16x8*)&qb[qbase];
        const s16x8 aq1 = *(const s16x8*)&qb[qbase + 32];

        for (int t = w; t <= qt; t += 4) {
            const int kc = t * 16;
            const size_t kbase = ((size_t)(kc + lr) * BATCH + b) * DMODEL + h * DH + lk8;
            const s16x8 bk0 = *(const s16x8*)&kb[kbase];
            const s16x8 bk1 = *(const s16x8*)&kb[kbase + 32];
            f32x4 s = {};
            s = __builtin_amdgcn_mfma_f32_16x16x32_bf16(aq0, bk0, s, 0, 0, 0);
            s = __builtin_amdgcn_mfma_f32_16x16x32_bf16(aq1, bk1, s, 0, 0, 0);
#pragma unroll
            for (int j = 0; j < 4; ++j) s_lds[4 * (lane >> 4) + j][kc + lr] = s[j];
        }
        __syncthreads();

        // ---- exact softmax, coverage accumulate, p -> bf16 LDS ----
#pragma unroll
        for (int r = 0; r < 4; ++r) {
            const int row = w * 4 + r;
            const int qg  = qt * 16 + row;
            float sv[16], ev[16];
            float m = -1e30f;
#pragma unroll
            for (int i = 0; i < 16; ++i) {
                const int col = lane + 64 * i;
                const float x = (col <= qg) ? s_lds[row][col] : -1e30f;
                sv[i] = x;
                m = fmaxf(m, x);
            }
#pragma unroll
            for (int off = 1; off < 64; off <<= 1) m = fmaxf(m, __shfl_xor(m, off));
            float sum = 0.f;
#pragma unroll
            for (int i = 0; i < 16; ++i) {
                const float e = (sv[i] > -1e29f) ? __expf(sv[i] - m) : 0.f;
                ev[i] = e;
                sum += e;
            }
#pragma unroll
            for (int off = 1; off < 64; off <<= 1) sum += __shfl_xor(sum, off);
            const float inv = 1.f / sum;
#pragma unroll
            for (int i = 0; i < 16; ++i) {
                const float p = ev[i] * inv;
                creg[r][i] += p * (1.f / NH);
                p_lds[row][lane + 64 * i] = f2b(p);
            }
        }
        __syncthreads();

        // ---- PV (k-tiles of 128, causal-skipped) ----
        f32x4 oacc = {};
        for (int k0 = 0; k0 <= qmax; k0 += 128) {
            {   // stage V^T tile: v[k0..k0+127][h*64..+64] -> vt_lds[d][k_local]
                const int kl = tid >> 1;
                const int d0 = (tid & 1) * 32;
                const unsigned short* src = &vb[((size_t)(k0 + kl) * BATCH + b) * DMODEL + h * DH + d0];
                union { uint4 v; unsigned short s[8]; } u0, u1, u2, u3;
                u0.v = ((const uint4*)src)[0];
                u1.v = ((const uint4*)src)[1];
                u2.v = ((const uint4*)src)[2];
                u3.v = ((const uint4*)src)[3];
#pragma unroll
                for (int i = 0; i < 8; ++i) {
                    vt_lds[d0 + i][kl]      = u0.s[i];
                    vt_lds[d0 + 8 + i][kl]  = u1.s[i];
                    vt_lds[d0 + 16 + i][kl] = u2.s[i];
                    vt_lds[d0 + 24 + i][kl] = u3.s[i];
                }
            }
            __syncthreads();
#pragma unroll
            for (int kk = 0; kk < 4; ++kk) {
                const s16x8 ap = *(const s16x8*)&p_lds[lr][k0 + kk * 32 + lk8];
                const s16x8 bv = *(const s16x8*)&vt_lds[w * 16 + lr][kk * 32 + lk8];
                oacc = __builtin_amdgcn_mfma_f32_16x16x32_bf16(ap, bv, oacc, 0, 0, 0);
            }
            __syncthreads();
        }

        {   // write attn-out (pre-Wo), bf16
            const int orow = qt * 16 + 4 * (lane >> 4);
            const int ocol = h * DH + w * 16 + lr;
#pragma unroll
            for (int j = 0; j < 4; ++j)
                ao[((size_t)(orow + j) * BATCH + b) * DMODEL + ocol] = f2b(oacc[j]);
        }
        __syncthreads();
    }

    // ---- coverage write: cov[b][q][k] ----
    float* covb = cov + ((size_t)b * LQ + qt * 16) * LQ;
#pragma unroll
    for (int r = 0; r < 4; ++r) {
        const int row = w * 4 + r;
#pragma unroll
        for (int i = 0; i < 16; ++i)
            covb[(size_t)row * LQ + lane + 64 * i] = creg[r][i];
    }
}

extern "C" void kernel_launch(void* const* d_in, const int* in_sizes, int n_in,
                              void* d_out, int out_size, void* d_ws, size_t ws_size,
                              hipStream_t stream) {
    (void)in_sizes; (void)n_in; (void)out_size; (void)ws_size;
    const float* query = (const float*)d_in[0];
    const float* key   = (const float*)d_in[1];
    const float* value = (const float*)d_in[2];
    const float* Wq    = (const float*)d_in[3];
    const float* Wk    = (const float*)d_in[4];
    const float* Wv    = (const float*)d_in[5];
    const float* Wo    = (const float*)d_in[6];
    // mask / rhs_mask / layer_idx unused: combined mask is provably pure causal.

    float* out = (float*)d_out;                           // (1024,4,1024)
    float* cov = out + (size_t)LQ * BATCH * DMODEL;       // (4,1024,1024)

    unsigned short* qb = (unsigned short*)d_ws;           // bf16 Q (scaled)
    unsigned short* kb = qb + (size_t)MROWS * DMODEL;     // bf16 K
    unsigned short* vb = kb + (size_t)MROWS * DMODEL;     // bf16 V
    unsigned short* ao = vb + (size_t)MROWS * DMODEL;     // bf16 attn-out

    dim3 grid(MROWS / 128, DMODEL / 128);
    dim3 blk(256);
    gemm_bt<true, false><<<grid, blk, 0, stream>>>(query, Wq, qb, 0.125f);  // dh^-0.5 folded in
    gemm_bt<true, false><<<grid, blk, 0, stream>>>(key,   Wk, kb, 1.0f);
    gemm_bt<true, false><<<grid, blk, 0, stream>>>(value, Wv, vb, 1.0f);
    attn_cov<<<dim3(LQ / 16, BATCH), blk, 0, stream>>>(qb, kb, vb, ao, cov);
    gemm_bt<false, true><<<grid, blk, 0, stream>>>(ao, Wo, out, 1.0f);
}